// Round 1
// baseline (4249.474 us; speedup 1.0000x reference)
//
#include <hip/hip_runtime.h>

#define NROWS 16384
#define DIN   784
#define DPAD  800
#define NLAT  1024
#define BM    64
#define ASTRIDE 1032   // bf16 elems per a_lds row: 2064 B = 516 dwords -> 2-way (free) bank skew
#define NITER 48       // 1 analytic step (u1 = 0.1*b) + 48 full steps = 49 steps

typedef __attribute__((ext_vector_type(8))) short  short8;
typedef __attribute__((ext_vector_type(4))) float  f32x4;

__device__ __forceinline__ unsigned short f2bf(float f) {
    unsigned int u = __builtin_bit_cast(unsigned int, f);
    u += 0x7fffu + ((u >> 16) & 1u);     // RNE
    return (unsigned short)(u >> 16);
}

// ---------------- prep kernels ----------------

__global__ void convert_w_kernel(const float* __restrict__ w, unsigned short* __restrict__ wbf) {
    int i = blockIdx.x * 256 + threadIdx.x;   // grid covers exactly 784*1024
    wbf[i] = f2bf(w[i]);
}

// wT[l][d] = w[d][l], padded to DPAD cols with zeros (for b = x@w B-fragments)
__global__ void transpose_pad_kernel(const float* __restrict__ w, unsigned short* __restrict__ wT) {
    __shared__ float tile[32][33];
    int d0 = blockIdx.x * 32;            // 25 blocks -> 0..800
    int l0 = blockIdx.y * 32;            // 32 blocks -> 0..1024
    int tx = threadIdx.x, ty = threadIdx.y;
    int d = d0 + ty;
    tile[ty][tx] = (d < DIN) ? w[(size_t)d * NLAT + l0 + tx] : 0.f;
    __syncthreads();
    wT[(size_t)(l0 + ty) * DPAD + d0 + tx] = f2bf(tile[tx][ty]);
}

// g = w^T w - I, bf16, row-major [1024][1024] (symmetric)
__global__ void gram_kernel(const float* __restrict__ w, unsigned short* __restrict__ g) {
    __shared__ float Wk[32][33];
    __shared__ float Wl[32][33];
    int k0 = blockIdx.x * 32, l0 = blockIdx.y * 32;
    int t = threadIdx.x;
    int c = t & 31, r8 = t >> 5;
    float acc[4] = {0.f, 0.f, 0.f, 0.f};
    for (int d0 = 0; d0 < DPAD; d0 += 32) {
        __syncthreads();
        #pragma unroll
        for (int rr = 0; rr < 4; ++rr) {
            int d = d0 + r8 + rr * 8;
            float vk = 0.f, vl = 0.f;
            if (d < DIN) {
                vk = w[(size_t)d * NLAT + k0 + c];
                vl = w[(size_t)d * NLAT + l0 + c];
            }
            Wk[r8 + rr * 8][c] = vk;
            Wl[r8 + rr * 8][c] = vl;
        }
        __syncthreads();
        #pragma unroll
        for (int dd = 0; dd < 32; ++dd) {
            float bl = Wl[dd][c];
            #pragma unroll
            for (int rr = 0; rr < 4; ++rr)
                acc[rr] += Wk[dd][r8 + rr * 8] * bl;
        }
    }
    #pragma unroll
    for (int rr = 0; rr < 4; ++rr) {
        int kr = k0 + r8 + rr * 8;
        int lc = l0 + c;
        float v = acc[rr] - ((kr == lc) ? 1.f : 0.f);
        g[(size_t)kr * NLAT + lc] = f2bf(v);
    }
}

// ---------------- fused main kernel ----------------
// 256 blocks x 512 threads. Block owns 64 rows. Wave wv owns cols [wv*128, wv*128+128).
// Invariant across iterations: u = -0.1 * acc.

__global__ __launch_bounds__(512, 2) void lca_main_kernel(
    const float* __restrict__ x,
    const unsigned short* __restrict__ g,
    const unsigned short* __restrict__ wbf,
    const unsigned short* __restrict__ wT,
    float* __restrict__ out)
{
    extern __shared__ char smem[];
    unsigned short* a_lds = (unsigned short*)smem;                        // [64][ASTRIDE] bf16
    unsigned short* x_lds = (unsigned short*)(smem + BM * ASTRIDE * 2);   // [2][64][40] bf16

    const int tid  = threadIdx.x;
    const int lane = tid & 63;
    const int wv   = tid >> 6;          // 0..7
    const int l15  = lane & 15;
    const int lg   = lane >> 4;         // 0..3
    const int rowbase = blockIdx.x * BM;
    const int wcol = wv * 128;

    f32x4 acc[4][8];
    #pragma unroll
    for (int mt = 0; mt < 4; ++mt)
        #pragma unroll
        for (int nt = 0; nt < 8; ++nt)
            acc[mt][nt] = (f32x4){0.f, 0.f, 0.f, 0.f};

    // ---- phase 0: acc <- b = x @ w (K padded 784->800, 25 chunks of 32) ----
    const int srow = tid >> 3;   // 0..63
    const int sq   = tid & 7;    // 0..7
    {
        int k = sq * 4;
        float4 v = make_float4(0.f, 0.f, 0.f, 0.f);
        if (k < DIN) v = *(const float4*)(x + (size_t)(rowbase + srow) * DIN + k);
        unsigned short* dst = x_lds + srow * 40 + sq * 4;
        *(unsigned int*)(dst)     = (unsigned int)f2bf(v.x) | ((unsigned int)f2bf(v.y) << 16);
        *(unsigned int*)(dst + 2) = (unsigned int)f2bf(v.z) | ((unsigned int)f2bf(v.w) << 16);
    }
    __syncthreads();
    for (int kc = 0; kc < 25; ++kc) {
        if (kc < 24) {
            int k = (kc + 1) * 32 + sq * 4;
            float4 v = make_float4(0.f, 0.f, 0.f, 0.f);
            if (k < DIN) v = *(const float4*)(x + (size_t)(rowbase + srow) * DIN + k);
            unsigned short* dst = x_lds + ((kc + 1) & 1) * (BM * 40) + srow * 40 + sq * 4;
            *(unsigned int*)(dst)     = (unsigned int)f2bf(v.x) | ((unsigned int)f2bf(v.y) << 16);
            *(unsigned int*)(dst + 2) = (unsigned int)f2bf(v.z) | ((unsigned int)f2bf(v.w) << 16);
        }
        const int buf = kc & 1;
        short8 af[4];
        #pragma unroll
        for (int mt = 0; mt < 4; ++mt)
            af[mt] = *(const short8*)(x_lds + buf * (BM * 40) + (mt * 16 + l15) * 40 + lg * 8);
        #pragma unroll
        for (int nt = 0; nt < 8; ++nt) {
            short8 bfr = *(const short8*)(wT + (size_t)(wcol + nt * 16 + l15) * DPAD + kc * 32 + lg * 8);
            #pragma unroll
            for (int mt = 0; mt < 4; ++mt)
                acc[mt][nt] = __builtin_amdgcn_mfma_f32_16x16x32_bf16(af[mt], bfr, acc[mt][nt], 0, 0, 0);
        }
        __syncthreads();
    }

    // pack b to bf16 pairs (64 regs), set acc = -b  (so u1 = -0.1*acc = 0.1*b : step 1)
    unsigned int bpk[4][8][2];
    #pragma unroll
    for (int mt = 0; mt < 4; ++mt)
        #pragma unroll
        for (int nt = 0; nt < 8; ++nt) {
            bpk[mt][nt][0] = (unsigned int)f2bf(acc[mt][nt][0]) | ((unsigned int)f2bf(acc[mt][nt][1]) << 16);
            bpk[mt][nt][1] = (unsigned int)f2bf(acc[mt][nt][2]) | ((unsigned int)f2bf(acc[mt][nt][3]) << 16);
            acc[mt][nt] = -acc[mt][nt];
        }

    const unsigned short* gl = g + (size_t)(wcol + l15) * NLAT + lg * 8;
    const int aoff_r = l15 * ASTRIDE + lg * 8;

    // ---- 48 full steps: A' = 0.9*A - b + threshold(-0.1*A) @ g ----
    for (int it = 0; it < NITER; ++it) {
        __syncthreads();   // prior iteration's a_lds reads complete
        #pragma unroll
        for (int mt = 0; mt < 4; ++mt)
            #pragma unroll
            for (int nt = 0; nt < 8; ++nt) {
                int colbase = wcol + nt * 16 + l15;
                #pragma unroll
                for (int r = 0; r < 4; ++r) {
                    int row = mt * 16 + lg * 4 + r;
                    float a = fmaxf(fmaf(-0.1f, acc[mt][nt][r], -0.3f), 0.f);
                    a_lds[row * ASTRIDE + colbase] = f2bf(a);
                }
            }
        __syncthreads();
        // C_init = 0.9*A - b
        #pragma unroll
        for (int mt = 0; mt < 4; ++mt)
            #pragma unroll
            for (int nt = 0; nt < 8; ++nt) {
                float b0 = __builtin_bit_cast(float, bpk[mt][nt][0] << 16);
                float b1 = __builtin_bit_cast(float, bpk[mt][nt][0] & 0xffff0000u);
                float b2 = __builtin_bit_cast(float, bpk[mt][nt][1] << 16);
                float b3 = __builtin_bit_cast(float, bpk[mt][nt][1] & 0xffff0000u);
                acc[mt][nt][0] = fmaf(0.9f, acc[mt][nt][0], -b0);
                acc[mt][nt][1] = fmaf(0.9f, acc[mt][nt][1], -b1);
                acc[mt][nt][2] = fmaf(0.9f, acc[mt][nt][2], -b2);
                acc[mt][nt][3] = fmaf(0.9f, acc[mt][nt][3], -b3);
            }
        for (int kc = 0; kc < 32; ++kc) {
            short8 af[4];
            #pragma unroll
            for (int mt = 0; mt < 4; ++mt)
                af[mt] = *(const short8*)(a_lds + mt * 16 * ASTRIDE + aoff_r + kc * 32);
            #pragma unroll
            for (int ng = 0; ng < 2; ++ng) {
                short8 bfr[4];
                #pragma unroll
                for (int j = 0; j < 4; ++j)
                    bfr[j] = *(const short8*)(gl + (size_t)(ng * 4 + j) * 16 * NLAT + kc * 32);
                #pragma unroll
                for (int j = 0; j < 4; ++j)
                    #pragma unroll
                    for (int mt = 0; mt < 4; ++mt)
                        acc[mt][ng * 4 + j] =
                            __builtin_amdgcn_mfma_f32_16x16x32_bf16(af[mt], bfr[j], acc[mt][ng * 4 + j], 0, 0, 0);
            }
        }
    }

    // ---- final a, then recon = a @ w^T ----
    __syncthreads();
    #pragma unroll
    for (int mt = 0; mt < 4; ++mt)
        #pragma unroll
        for (int nt = 0; nt < 8; ++nt) {
            int colbase = wcol + nt * 16 + l15;
            #pragma unroll
            for (int r = 0; r < 4; ++r) {
                int row = mt * 16 + lg * 4 + r;
                float a = fmaxf(fmaf(-0.1f, acc[mt][nt][r], -0.3f), 0.f);
                a_lds[row * ASTRIDE + colbase] = f2bf(a);
            }
        }
    __syncthreads();
    for (int nt = wv; nt < 49; nt += 8) {     // 49 N-tiles of 16 = 784 output cols
        f32x4 racc[4];
        #pragma unroll
        for (int mt = 0; mt < 4; ++mt) racc[mt] = (f32x4){0.f, 0.f, 0.f, 0.f};
        for (int kc = 0; kc < 32; ++kc) {
            short8 af[4];
            #pragma unroll
            for (int mt = 0; mt < 4; ++mt)
                af[mt] = *(const short8*)(a_lds + mt * 16 * ASTRIDE + aoff_r + kc * 32);
            // B[k][n] = wT[k][n] = w[n][k] -> contiguous in k from row-major w_bf16
            short8 bfr = *(const short8*)(wbf + (size_t)(nt * 16 + l15) * NLAT + kc * 32 + lg * 8);
            #pragma unroll
            for (int mt = 0; mt < 4; ++mt)
                racc[mt] = __builtin_amdgcn_mfma_f32_16x16x32_bf16(af[mt], bfr, racc[mt], 0, 0, 0);
        }
        #pragma unroll
        for (int mt = 0; mt < 4; ++mt)
            #pragma unroll
            for (int r = 0; r < 4; ++r)
                out[(size_t)(rowbase + mt * 16 + lg * 4 + r) * DIN + nt * 16 + l15] = racc[mt][r];
    }
}

// ---------------- launch ----------------

extern "C" void kernel_launch(void* const* d_in, const int* in_sizes, int n_in,
                              void* d_out, int out_size, void* d_ws, size_t ws_size,
                              hipStream_t stream) {
    const float* x = (const float*)d_in[0];
    const float* w = (const float*)d_in[1];
    float* out = (float*)d_out;
    char* ws = (char*)d_ws;

    unsigned short* g   = (unsigned short*)(ws);                                  // 2 MB
    unsigned short* wbf = (unsigned short*)(ws + (2u << 20));                     // 784*1024*2
    unsigned short* wT  = (unsigned short*)(ws + (2u << 20) + DIN * NLAT * 2);    // 1024*800*2

    convert_w_kernel<<<3136, 256, 0, stream>>>(w, wbf);
    transpose_pad_kernel<<<dim3(25, 32), dim3(32, 32), 0, stream>>>(w, wT);
    gram_kernel<<<dim3(32, 32), 256, 0, stream>>>(w, g);

    const int smem_bytes = BM * ASTRIDE * 2 + 2 * BM * 40 * 2;   // 142336
    hipFuncSetAttribute((const void*)lca_main_kernel,
                        hipFuncAttributeMaxDynamicSharedMemorySize, smem_bytes);
    lca_main_kernel<<<256, 512, smem_bytes, stream>>>(x, g, wbf, wT, out);
}